// Round 11
// baseline (120.503 us; speedup 1.0000x reference)
//
#include <hip/hip_runtime.h>

// Problem constants (fixed by the reference module)
#define B_ 16
#define L_ 2048
#define D_ 128
#define GROUP_ 16
#define NG_ (L_ / GROUP_)   // 128

typedef float v2 __attribute__((ext_vector_type(2)));

// DPP-based butterfly add within each 16-lane row (full-rate VALU, no LDS).
template<int CTRL>
__device__ __forceinline__ float dpp_add(float v) {
    int x = __builtin_amdgcn_update_dpp(0, __float_as_int(v), CTRL, 0xF, 0xF, false);
    return v + __int_as_float(x);
}
__device__ __forceinline__ float row16_sum(float v) {
    v = dpp_add<0xB1>(v);   // quad_perm(1,0,3,2)  ~ xor 1
    v = dpp_add<0x4E>(v);   // quad_perm(2,3,0,1)  ~ xor 2
    v = dpp_add<0x141>(v);  // row_half_mirror     ~ xor 4
    v = dpp_add<0x140>(v);  // row_mirror          ~ xor 8
    return v;
}

#define PK_FMA(a,b,c) __builtin_elementwise_fma((a),(b),(c))
#define PK_MIN(a,b)   __builtin_elementwise_min((a),(b))
#define PK_MAX(a,b)   __builtin_elementwise_max((a),(b))

// Pade [5/4] tanh pieces: num = v*(945+105w+w^2), den = 945+420w+15w^2,
// w = min(v*v, 36) -> t = clamp(num/den, -1, 1). Max err ~1.1e-3 (|v|~3.6);
// w-clamp keeps den <= 3.6e4 so 4-way den products never overflow, and for
// |v|>6 t>1 -> the +-1 clamp gives the exact saturation limit (inf-safe).
__device__ __forceinline__ void tanh_nd(v2 v, v2& num, v2& den) {
    const v2 c105 = (v2){105.0f, 105.0f};
    const v2 c945 = (v2){945.0f, 945.0f};
    const v2 c420 = (v2){420.0f, 420.0f};
    const v2 c15  = (v2){15.0f, 15.0f};
    const v2 c36  = (v2){36.0f, 36.0f};
    v2 w = PK_MIN(v * v, c36);
    num = v * PK_FMA(w, w + c105, c945);
    den = PK_FMA(w, PK_FMA(w, c15, c420), c945);
}

// Packed Montgomery: r[k] = 1/d[k] for 4 v2 pairs with 2 scalar v_rcp.
__device__ __forceinline__ void rcp4v2(const v2 d[4], v2 r[4]) {
    v2 P1 = d[0] * d[1];
    v2 P2 = P1 * d[2];
    v2 P3 = P2 * d[3];
    v2 R  = (v2){__builtin_amdgcn_rcpf(P3.x), __builtin_amdgcn_rcpf(P3.y)};
    r[3] = P2 * R;
    v2 R2 = R * d[3];    // 1/P2
    r[2] = P1 * R2;
    v2 R1 = R2 * d[2];   // 1/P1
    r[1] = d[0] * R1;
    r[0] = R1 * d[1];
}

// One block per (b,g) group. 256 threads = 16 rows x 16 lanes, 8 elems/thread.
//
// R10 audit: issue/wave-step ~510 cyc, ~75% is the 32 trans ops (16 exp2 +
// 16 rcp @ ~12 cyc wave64). This round kills trans: tanh via Pade[5/4]
// rational (no exp2) + packed-Montgomery rcp batching (8 rcp -> 2 per pass).
// 32 trans -> 4 trans + ~50 pk ops: issue ~370 cyc/wave-step (-27%).
__global__ __launch_bounds__(256, 4) void ncn_kernel(
    const float* __restrict__ x,       // (B, L, D)
    const int*   __restrict__ gt,      // (B, L) permutation
    const int*   __restrict__ ctxlens, // (B,)
    const float* __restrict__ W,       // (2D,)
    const float* __restrict__ nalpha,  // (2,)
    const float* __restrict__ ngamma,  // (2D,)
    const float* __restrict__ nbeta,   // (2D,)
    float* __restrict__ out)           // (2, B, L, D) concat: yi_out, ya_out
{
    const int blk = blockIdx.x;
    const int b   = blk >> 7;      // / NG_
    const int g   = blk & (NG_ - 1);
    const int tid = threadIdx.x;
    const int row = tid >> 4;      // 0..15 (token within group)
    const int rl  = tid & 15;      // 0..15 (lane within row)
    const int d0  = rl << 3;       // 8 d-elements per thread

    __shared__ float s_xj[2][D_];  // double-buffered broadcast row

    const float a1 = nalpha[0];
    const float a2 = nalpha[1];
    const float h1 = 0.5f * a1;    // v1 = a1*T = h1*T2 (T2 = 2T)
    const v2 h1v = (v2){h1, h1};
    const v2 h2v = (v2){a2, a2};
    const v2 onev  = (v2){1.0f, 1.0f};
    const v2 monev = (v2){-1.0f, -1.0f};
    const v2 leak  = (v2){0.01f, 0.01f};

    // Per-chunk constants in registers (reused 16x), as packed v2 pairs.
    v2 Wi[4], Wj[4], g1v[4], b1v[4], g2v[4], b2v[4];
    {
        float4 wA = *(const float4*)(W + d0);
        float4 wB = *(const float4*)(W + d0 + 4);
        float4 vA = *(const float4*)(W + D_ + d0);
        float4 vB = *(const float4*)(W + D_ + d0 + 4);
        Wi[0] = (v2){wA.x, wA.y}; Wi[1] = (v2){wA.z, wA.w};
        Wi[2] = (v2){wB.x, wB.y}; Wi[3] = (v2){wB.z, wB.w};
        Wj[0] = (v2){vA.x, vA.y}; Wj[1] = (v2){vA.z, vA.w};
        Wj[2] = (v2){vB.x, vB.y}; Wj[3] = (v2){vB.z, vB.w};

        float4 g1A = *(const float4*)(ngamma + d0);
        float4 g1B = *(const float4*)(ngamma + d0 + 4);
        float4 g2A = *(const float4*)(ngamma + D_ + d0);
        float4 g2B = *(const float4*)(ngamma + D_ + d0 + 4);
        float4 b1A = *(const float4*)(nbeta + d0);
        float4 b1B = *(const float4*)(nbeta + d0 + 4);
        float4 b2A = *(const float4*)(nbeta + D_ + d0);
        float4 b2B = *(const float4*)(nbeta + D_ + d0 + 4);
        g1v[0]=(v2){g1A.x,g1A.y}; g1v[1]=(v2){g1A.z,g1A.w};
        g1v[2]=(v2){g1B.x,g1B.y}; g1v[3]=(v2){g1B.z,g1B.w};
        b1v[0]=(v2){b1A.x,b1A.y}; b1v[1]=(v2){b1A.z,b1A.w};
        b1v[2]=(v2){b1B.x,b1B.y}; b1v[3]=(v2){b1B.z,b1B.w};
        g2v[0]=(v2){g2A.x,g2A.y}; g2v[1]=(v2){g2A.z,g2A.w};
        g2v[2]=(v2){g2B.x,g2B.y}; g2v[3]=(v2){g2B.z,g2B.w};
        b2v[0]=(v2){b2A.x,b2A.y}; b2v[1]=(v2){b2A.z,b2A.w};
        b2v[2]=(v2){b2B.x,b2B.y}; b2v[3]=(v2){b2B.z,b2B.w};
    }

    // Gather this row's token
    const int l   = g * GROUP_ + row;
    const int tok = gt[b * L_ + l];
    const float* xp = x + ((size_t)(b * L_ + tok)) * D_ + d0;

    v2 xi[4], xa[4];
    {
        float4 xA = *(const float4*)xp;
        float4 xB = *(const float4*)(xp + 4);
        xi[0] = (v2){xA.x, xA.y}; xi[1] = (v2){xA.z, xA.w};
        xi[2] = (v2){xB.x, xB.y}; xi[3] = (v2){xB.z, xB.w};
    }
#pragma unroll
    for (int k = 0; k < 4; ++k) xa[k] = (v2){0.0f, 0.0f};

    // Row 0 publishes its initial xi into buffer 0
    if (row == 0) {
        *(v2*)&s_xj[0][d0]     = xi[0];
        *(v2*)&s_xj[0][d0 + 2] = xi[1];
        *(v2*)&s_xj[0][d0 + 4] = xi[2];
        *(v2*)&s_xj[0][d0 + 6] = xi[3];
    }
    __syncthreads();

    for (int j = 0; j < GROUP_; ++j) {
        const int p = j & 1;

        v2 xjv[4];
        {
            float4 tA = *(const float4*)&s_xj[p][d0];
            float4 tB = *(const float4*)&s_xj[p][d0 + 4];
            xjv[0] = (v2){tA.x, tA.y}; xjv[1] = (v2){tA.z, tA.w};
            xjv[2] = (v2){tB.x, tB.y}; xjv[3] = (v2){tB.z, tB.w};
        }

        // sim = dot(xi,Wi) + dot(xj,Wj): packed FMAs, one DPP reduce.
        v2 sv = (v2){0.0f, 0.0f};
#pragma unroll
        for (int k = 0; k < 4; ++k) sv = PK_FMA(xi[k],  Wi[k], sv);
#pragma unroll
        for (int k = 0; k < 4; ++k) sv = PK_FMA(xjv[k], Wj[k], sv);
        const float sim = row16_sum(sv.x + sv.y);
        const v2 simv = (v2){sim, sim};

        // Pass A: tanh1 numerators/denominators (v1 = h1*(xi + sim*xj))
        v2 num[4], den[4], r[4];
#pragma unroll
        for (int k = 0; k < 4; ++k) {
            v2 T2 = PK_FMA(simv, xjv[k], xi[k]);
            tanh_nd(h1v * T2, num[k], den[k]);
        }
        rcp4v2(den, r);

        // Pass B: t1 -> leaky-relu -> xa; then tanh2 num/den (v2 = a2*xa)
#pragma unroll
        for (int k = 0; k < 4; ++k) {
            v2 t  = PK_MIN(PK_MAX(num[k] * r[k], monev), onev);
            v2 tn = PK_FMA(g1v[k], t, b1v[k]);       // g1*tanh(a1*T)+b1
            v2 Fv = PK_MAX(tn, tn * leak);           // leaky relu
            xa[k] += Fv;
            tanh_nd(h2v * xa[k], num[k], den[k]);
        }
        rcp4v2(den, r);

        // Pass C: xi += g2*tanh(a2*xa) + b2
#pragma unroll
        for (int k = 0; k < 4; ++k) {
            v2 t = PK_MIN(PK_MAX(num[k] * r[k], monev), onev);
            xi[k] = PK_FMA(g2v[k], t, xi[k] + b2v[k]);
        }

        // Next step's broadcaster writes the OTHER buffer; the single
        // barrier orders both visibility and WAR reuse.
        if (j + 1 < GROUP_ && row == j + 1) {
            *(v2*)&s_xj[p ^ 1][d0]     = xi[0];
            *(v2*)&s_xj[p ^ 1][d0 + 2] = xi[1];
            *(v2*)&s_xj[p ^ 1][d0 + 4] = xi[2];
            *(v2*)&s_xj[p ^ 1][d0 + 6] = xi[3];
        }
        __syncthreads();
    }

    const bool valid = (g * GROUP_) < ctxlens[b];
    if (!valid) {
#pragma unroll
        for (int k = 0; k < 4; ++k) { xi[k] = (v2){0,0}; xa[k] = (v2){0,0}; }
    }

    // Scatter back through the permutation (bijective -> every out elem written)
    float* o1 = out + ((size_t)(b * L_ + tok)) * D_ + d0;
    float* o2 = o1 + (size_t)B_ * L_ * D_;
    float4 s1A = {xi[0].x, xi[0].y, xi[1].x, xi[1].y};
    float4 s1B = {xi[2].x, xi[2].y, xi[3].x, xi[3].y};
    float4 s2A = {xa[0].x, xa[0].y, xa[1].x, xa[1].y};
    float4 s2B = {xa[2].x, xa[2].y, xa[3].x, xa[3].y};
    *(float4*)o1       = s1A;
    *(float4*)(o1 + 4) = s1B;
    *(float4*)o2       = s2A;
    *(float4*)(o2 + 4) = s2B;
}

extern "C" void kernel_launch(void* const* d_in, const int* in_sizes, int n_in,
                              void* d_out, int out_size, void* d_ws, size_t ws_size,
                              hipStream_t stream) {
    const float* x  = (const float*)d_in[0];
    const int*   gt = (const int*)d_in[1];
    const int*   cl = (const int*)d_in[2];
    const float* W  = (const float*)d_in[3];
    const float* na = (const float*)d_in[4];
    const float* ng = (const float*)d_in[5];
    const float* nb = (const float*)d_in[6];
    float* out = (float*)d_out;

    ncn_kernel<<<B_ * NG_, 256, 0, stream>>>(x, gt, cl, W, na, ng, nb, out);
}